// Round 1
// baseline (1629.606 us; speedup 1.0000x reference)
//
#include <hip/hip_runtime.h>
#include <hip/hip_bf16.h>

typedef _Float16 f16;
typedef _Float16 f16x8 __attribute__((ext_vector_type(8)));
typedef _Float16 f16x4 __attribute__((ext_vector_type(4)));
typedef float    f32x4 __attribute__((ext_vector_type(4)));

#define MFMA(a,b,c) __builtin_amdgcn_mfma_f32_16x16x32_f16((a),(b),(c),0,0,0)

#define BATCH 1024
#define T_HIST 50
#define ENC_IN 96
#define ENC_H 128
#define G4 512
#define CDE_H 64
#define NCH 33
#define MLP_H 128
#define NZ 10000
#define NSTEP 16
#define SROWS (BATCH*T_HIST)

__device__ __forceinline__ float sigf(float x){ return 1.f/(1.f+__expf(-x)); }
__device__ __forceinline__ float tanhfast(float x){
  float ax=fabsf(x), e=__expf(-2.f*ax);
  float t=1.f-2.f*e/(1.f+e);
  return x<0.f ? -t : t;
}

// Dormand-Prince tableau
__device__ const float RK_A[6][5] = {
  {0.f,0.f,0.f,0.f,0.f},
  {0.2f,0.f,0.f,0.f,0.f},
  {(float)(3.0/40.0),(float)(9.0/40.0),0.f,0.f,0.f},
  {(float)(44.0/45.0),(float)(-56.0/15.0),(float)(32.0/9.0),0.f,0.f},
  {(float)(19372.0/6561.0),(float)(-25360.0/2187.0),(float)(64448.0/6561.0),(float)(-212.0/729.0),0.f},
  {(float)(9017.0/3168.0),(float)(-355.0/33.0),(float)(46732.0/5247.0),(float)(49.0/176.0),(float)(-5103.0/18656.0)}};
__device__ const float RK_C[6] = {0.f,0.2f,0.3f,0.8f,(float)(8.0/9.0),1.f};
__device__ const float RK_B[6] = {(float)(35.0/384.0),0.f,(float)(500.0/1113.0),(float)(125.0/192.0),(float)(-2187.0/6784.0),(float)(11.0/84.0)};

// ---------------------------------------------------------------------------
// Pack weights (fp32 -> fp16 B-fragment layout [ntile][kk][lane][8])
// B-frag: lane holds B[k = kk*32 + (lane>>4)*8 + j][n = ntile*16 + (lane&15)]
// where B[k][n] = W[n][k] (W row-major (N,K)).  W2 rows are permuted so that
// output column col' = q*64 + h  maps to original row h*33+q.
// ---------------------------------------------------------------------------
__global__ __launch_bounds__(256) void pack_weights(
    const float* __restrict__ wih0, const float* __restrict__ whh0,
    const float* __restrict__ wih1, const float* __restrict__ whh1,
    const float* __restrict__ w1,   const float* __restrict__ wmap,
    const float* __restrict__ w2,   const float* __restrict__ wpred,
    f16* fwih0, f16* fwhh0, f16* fwih1, f16* fwhh1,
    f16* fw1, f16* fwmap, f16* fw2, f16* fwpred)
{
  int bi = blockIdx.x;
  const float* src; f16* dst; int KK, K, n; bool perm=false;
  if      (bi < 32)  { src=wih0;  dst=fwih0;  KK=3; K=96;  n=bi; }
  else if (bi < 64)  { src=whh0;  dst=fwhh0;  KK=4; K=128; n=bi-32; }
  else if (bi < 96)  { src=wih1;  dst=fwih1;  KK=4; K=128; n=bi-64; }
  else if (bi < 128) { src=whh1;  dst=fwhh1;  KK=4; K=128; n=bi-96; }
  else if (bi < 136) { src=w1;    dst=fw1;    KK=2; K=64;  n=bi-128; }
  else if (bi < 140) { src=wmap;  dst=fwmap;  KK=4; K=128; n=bi-136; }
  else if (bi < 272) { src=w2;    dst=fw2;    KK=4; K=128; n=bi-140; perm=true; }
  else               { src=wpred; dst=fwpred; KK=2; K=64;  n=bi-272; }
  int kkI = threadIdx.x>>6, lane = threadIdx.x&63;
  if (kkI >= KK) return;
  int col = n*16 + (lane&15);
  int row = perm ? ((col&63)*NCH + (col>>6)) : col;
  int k0  = kkI*32 + (lane>>4)*8;
  f16* o = dst + (((size_t)n*KK + kkI)*64 + lane)*8;
  const float* s = src + (size_t)row*K + k0;
  #pragma unroll
  for(int j=0;j<8;j++) o[j] = (f16)s[j];
}

// ---------------------------------------------------------------------------
// G0 = history(b-major rows) @ Wih0^T + (bih+bhh), stored t-major [t][b][512] fp16
// ---------------------------------------------------------------------------
__global__ __launch_bounds__(256) void gemm_g0(
    const float* __restrict__ X, const f16* __restrict__ Bf,
    const float* __restrict__ bih, const float* __restrict__ bhh,
    f16* __restrict__ G)
{
  int m = blockIdx.x;
  int w = threadIdx.x>>6, lane = threadIdx.x&63;
  int lm = lane&15, quad = lane>>4;
  int arow = m*16 + lm;
  f16x8 af[3];
  #pragma unroll
  for(int kk=0;kk<3;kk++){
    const float* p = X + (size_t)arow*ENC_IN + kk*32 + quad*8;
    f16x8 v;
    #pragma unroll
    for(int j=0;j<8;j++) v[j] = (f16)p[j];
    af[kk]=v;
  }
  const f16x8* bf8 = (const f16x8*)Bf;
  #pragma unroll
  for(int jt=0;jt<8;jt++){
    int n = w*8 + jt;
    f32x4 acc = {0.f,0.f,0.f,0.f};
    #pragma unroll
    for(int kk=0;kk<3;kk++)
      acc = MFMA(af[kk], bf8[(n*3+kk)*64 + lane], acc);
    int col = n*16 + lm;
    float bias = bih[col] + bhh[col];
    #pragma unroll
    for(int r=0;r<4;r++){
      int srow = m*16 + quad*4 + r;
      int b = srow / T_HIST, t = srow - b*T_HIST;
      G[((size_t)t*BATCH + b)*G4 + col] = (f16)(acc[r] + bias);
    }
  }
}

// G1 = seq0(t-major rows, fp16) @ Wih1^T + (bih+bhh), stored [same rows][512]
__global__ __launch_bounds__(256) void gemm_g1(
    const f16* __restrict__ X, const f16* __restrict__ Bf,
    const float* __restrict__ bih, const float* __restrict__ bhh,
    f16* __restrict__ G)
{
  int m = blockIdx.x;
  int w = threadIdx.x>>6, lane = threadIdx.x&63;
  int lm = lane&15, quad = lane>>4;
  int arow = m*16 + lm;
  f16x8 af[4];
  #pragma unroll
  for(int kk=0;kk<4;kk++)
    af[kk] = *(const f16x8*)(X + (size_t)arow*ENC_H + kk*32 + quad*8);
  const f16x8* bf8 = (const f16x8*)Bf;
  #pragma unroll
  for(int jt=0;jt<8;jt++){
    int n = w*8 + jt;
    f32x4 acc = {0.f,0.f,0.f,0.f};
    #pragma unroll
    for(int kk=0;kk<4;kk++)
      acc = MFMA(af[kk], bf8[(n*4+kk)*64 + lane], acc);
    int col = n*16 + lm;
    float bias = bih[col]+bhh[col];
    #pragma unroll
    for(int r=0;r<4;r++){
      int srow = m*16 + quad*4 + r;
      G[(size_t)srow*G4 + col] = (f16)(acc[r]+bias);
    }
  }
}

// ---------------------------------------------------------------------------
// Persistent LSTM recurrence: 64 blocks x 16 batch rows, 50 steps.
// Whh B-fragments live in VGPRs (8 tiles x 4 kk per wave). h in LDS (fp16).
// layer==0: writes seq0[t][b][128].  layer==1: fused W_map+tanh epilogue -> z0
// ---------------------------------------------------------------------------
__global__ __launch_bounds__(256,1) void lstm_kernel(
    const f16* __restrict__ G, const f16* __restrict__ Whhf,
    f16* __restrict__ seqout,
    const f16* __restrict__ Wmapf, const float* __restrict__ bmap,
    float* __restrict__ z0, int layer)
{
  __shared__ __align__(16) f16 hbuf[16][136];
  int w = threadIdx.x>>6, lane = threadIdx.x&63;
  int lm = lane&15, quad = lane>>4;
  int row0 = blockIdx.x*16;

  const f16x8* wf8 = (const f16x8*)Whhf;
  f16x8 Bf[8][4];
  #pragma unroll
  for(int j=0;j<8;j++){
    int n = w + 4*j;
    #pragma unroll
    for(int kk=0;kk<4;kk++)
      Bf[j][kk] = wf8[(n*4+kk)*64 + lane];
  }
  for(int i=threadIdx.x;i<16*136;i+=256) ((f16*)hbuf)[i] = (f16)0.f;
  float cst[2][4];
  #pragma unroll
  for(int mh=0;mh<2;mh++){
    #pragma unroll
    for(int r=0;r<4;r++) cst[mh][r]=0.f;
  }
  __syncthreads();

  for(int t=0;t<T_HIST;t++){
    f16x8 af[4];
    #pragma unroll
    for(int kk=0;kk<4;kk++)
      af[kk] = *(const f16x8*)&hbuf[lm][kk*32 + quad*8];
    f32x4 acc[8];
    const f16* Gt = G + ((size_t)t*BATCH + row0)*G4;
    #pragma unroll
    for(int j=0;j<8;j++){
      int col = (w+4*j)*16 + lm;
      #pragma unroll
      for(int r=0;r<4;r++)
        acc[j][r] = (float)Gt[(quad*4+r)*G4 + col];
    }
    #pragma unroll
    for(int j=0;j<8;j++){
      #pragma unroll
      for(int kk=0;kk<4;kk++)
        acc[j] = MFMA(af[kk], Bf[j][kk], acc[j]);
    }
    __syncthreads();   // all h reads done before rewrite
    #pragma unroll
    for(int mh=0;mh<2;mh++){
      int hcol = (w+4*mh)*16 + lm;
      #pragma unroll
      for(int r=0;r<4;r++){
        float gi = acc[0+mh][r], gf = acc[2+mh][r], gg = acc[4+mh][r], go = acc[6+mh][r];
        float c = sigf(gf)*cst[mh][r] + sigf(gi)*tanhfast(gg);
        float h = sigf(go)*tanhfast(c);
        cst[mh][r]=c;
        hbuf[quad*4+r][hcol] = (f16)h;
        if(layer==0)
          seqout[((size_t)t*BATCH + row0 + quad*4 + r)*ENC_H + hcol] = (f16)h;
      }
    }
    __syncthreads();
  }
  if(layer==1){
    f16x8 af[4];
    #pragma unroll
    for(int kk=0;kk<4;kk++)
      af[kk] = *(const f16x8*)&hbuf[lm][kk*32+quad*8];
    const f16x8* mf8 = (const f16x8*)Wmapf;
    float bm = bmap[w*16+lm];
    f32x4 acc = {bm,bm,bm,bm};
    #pragma unroll
    for(int kk=0;kk<4;kk++)
      acc = MFMA(af[kk], mf8[(w*4+kk)*64+lane], acc);
    #pragma unroll
    for(int r=0;r<4;r++)
      z0[(size_t)(row0+quad*4+r)*CDE_H + w*16+lm] = tanhfast(acc[r]);
  }
}

// ---------------------------------------------------------------------------
// Persistent CDE: 64 blocks x 16 rows; 16 RK steps x 6 stages, fully in-block.
// Per stage: dXdt -> combo+layernorm -> GEMM1(relu) -> GEMM2(tanh)+einsum.
// W2 fragments streamed from L2 (row-permuted so einsum accumulates in regs).
// ---------------------------------------------------------------------------
__global__ __launch_bounds__(256,1) void cde_kernel(
    const float* __restrict__ z0, const float* __restrict__ coeffs,
    const float* __restrict__ times,
    const f16* __restrict__ W1f, const f16* __restrict__ W2f,
    const float* __restrict__ b1, const float* __restrict__ b2,
    const float* __restrict__ gamma_, const float* __restrict__ beta_,
    float* __restrict__ zf)
{
  __shared__ __align__(16) float zbuf[16][68];
  __shared__ __align__(16) float kbuf[6][16][68];
  __shared__ __align__(16) f16   znbuf[16][72];
  __shared__ __align__(16) f16   abuf[16][136];
  __shared__ __align__(16) float dxbuf[16][36];
  __shared__ __align__(16) f16x8 w1lds[8*2*64];

  int tid = threadIdx.x;
  int w = tid>>6, lane = tid&63, lm = lane&15, quad = lane>>4;
  int row0 = blockIdx.x*16;

  for(int i=tid;i<8*2*64;i+=256) w1lds[i] = ((const f16x8*)W1f)[i];

  int crow = w*4 + quad;     // combo-mapping: each thread owns 4 cols of one row
  int ccol = lm*4;
  {
    f32x4 v = *(const f32x4*)(z0 + (size_t)(row0+crow)*CDE_H + ccol);
    *(f32x4*)&zbuf[crow][ccol] = v;
  }
  float t0 = times[0], t1 = times[1];
  float dt = (t1-t0)/(float)NSTEP, seg = (t1-t0)*0.25f;
  float gam[4], bet[4];
  #pragma unroll
  for(int j=0;j<4;j++){ gam[j]=gamma_[ccol+j]; bet[j]=beta_[ccol+j]; }
  __syncthreads();

  for(int istep=0;istep<NSTEP;istep++){
    for(int s=0;s<6;s++){
      float ts = t0 + ((float)istep + RK_C[s])*dt;
      // ---- dXdt into LDS
      {
        int idxt = (int)floorf((ts-t0)/seg);
        idxt = min(3, max(0, idxt));
        float u = ts - t0 - (float)idxt*seg;
        for(int idx=tid; idx<16*NCH; idx+=256){
          int r = idx/NCH, q = idx - r*NCH;
          const float* cc = coeffs + (((size_t)(row0+r)*4 + idxt)*4)*NCH + q;
          float c1 = cc[NCH], c2 = cc[2*NCH], c3 = cc[3*NCH];
          dxbuf[r][q] = c1 + 2.f*c2*u + 3.f*c3*u*u;
        }
      }
      // ---- stage combo + layernorm -> zn (fp16)
      {
        f32x4 v = *(const f32x4*)&zbuf[crow][ccol];
        for(int j=0;j<s;j++){
          float aj = dt*RK_A[s][j];
          f32x4 kv = *(const f32x4*)&kbuf[j][crow][ccol];
          v[0]+=aj*kv[0]; v[1]+=aj*kv[1]; v[2]+=aj*kv[2]; v[3]+=aj*kv[3];
        }
        float sum = v[0]+v[1]+v[2]+v[3];
        float ssq = v[0]*v[0]+v[1]*v[1]+v[2]*v[2]+v[3]*v[3];
        #pragma unroll
        for(int m=1;m<16;m<<=1){
          sum += __shfl_xor(sum, m);
          ssq += __shfl_xor(ssq, m);
        }
        float mu   = sum*(1.f/CDE_H);
        float var  = ssq*(1.f/CDE_H) - mu*mu;
        float rstd = rsqrtf(var + 1e-5f);
        f16x4 zn;
        #pragma unroll
        for(int j=0;j<4;j++)
          zn[j] = (f16)(((v[j]-mu)*rstd)*gam[j] + bet[j]);
        *(f16x4*)&znbuf[crow][ccol] = zn;
      }
      __syncthreads();
      // ---- GEMM1: a = relu(zn @ W1^T + b1)   (16x64 -> 16x128)
      {
        f16x8 af[2];
        #pragma unroll
        for(int kk=0;kk<2;kk++)
          af[kk] = *(const f16x8*)&znbuf[lm][kk*32+quad*8];
        #pragma unroll
        for(int jt=0;jt<2;jt++){
          int n = w + 4*jt;
          f32x4 acc={0.f,0.f,0.f,0.f};
          #pragma unroll
          for(int kk=0;kk<2;kk++)
            acc = MFMA(af[kk], w1lds[(n*2+kk)*64+lane], acc);
          int col = n*16+lm;
          float bb = b1[col];
          #pragma unroll
          for(int r=0;r<4;r++){
            float a = acc[r]+bb;
            abuf[quad*4+r][col] = (f16)(a>0.f? a:0.f);
          }
        }
      }
      __syncthreads();
      // ---- GEMM2 + tanh + einsum (k accumulated in regs; wave w owns h-slice)
      {
        f16x8 af[4];
        #pragma unroll
        for(int kk=0;kk<4;kk++)
          af[kk] = *(const f16x8*)&abuf[lm][kk*32+quad*8];
        const f16x8* w2f8 = (const f16x8*)W2f;
        int h = w*16+lm;
        f32x4 kacc = {0.f,0.f,0.f,0.f};
        f16x8 bc[4], bn[4];
        #pragma unroll
        for(int kk=0;kk<4;kk++) bc[kk] = w2f8[((size_t)(w)*4+kk)*64+lane];
        for(int j=0;j<NCH;j++){
          if(j+1<NCH){
            int n2 = 4*(j+1)+w;
            #pragma unroll
            for(int kk=0;kk<4;kk++) bn[kk] = w2f8[((size_t)n2*4+kk)*64+lane];
          }
          float b2v = b2[h*NCH + j];
          f32x4 acc = {b2v,b2v,b2v,b2v};
          #pragma unroll
          for(int kk=0;kk<4;kk++) acc = MFMA(af[kk], bc[kk], acc);
          #pragma unroll
          for(int r=0;r<4;r++){
            float f = tanhfast(acc[r]);
            kacc[r] += f * dxbuf[quad*4+r][j];
          }
          #pragma unroll
          for(int kk=0;kk<4;kk++) bc[kk]=bn[kk];
        }
        #pragma unroll
        for(int r=0;r<4;r++)
          kbuf[s][quad*4+r][h] = kacc[r];
      }
      __syncthreads();
    }
    // ---- z update (each thread owns its cells)
    {
      f32x4 v = *(const f32x4*)&zbuf[crow][ccol];
      #pragma unroll
      for(int j=0;j<6;j++){
        if(j==1) continue;
        float bj = dt*RK_B[j];
        f32x4 kv = *(const f32x4*)&kbuf[j][crow][ccol];
        v[0]+=bj*kv[0]; v[1]+=bj*kv[1]; v[2]+=bj*kv[2]; v[3]+=bj*kv[3];
      }
      *(f32x4*)&zbuf[crow][ccol] = v;
      if(istep==NSTEP-1)
        *(f32x4*)(zf + (size_t)(row0+crow)*CDE_H + ccol) = v;
    }
    __syncthreads();
  }
}

// ---------------------------------------------------------------------------
// out = zf @ Wpred^T + bpred   (1024 x 10000, fp32 out)
// ---------------------------------------------------------------------------
__global__ __launch_bounds__(256) void gemm_out(
    const float* __restrict__ zfin, const f16* __restrict__ Wpf,
    const float* __restrict__ bpred, float* __restrict__ out)
{
  int m = blockIdx.x, g = blockIdx.y;
  int w = threadIdx.x>>6, lane = threadIdx.x&63, lm=lane&15, quad=lane>>4;
  int arow = m*16+lm;
  f16x8 af[2];
  #pragma unroll
  for(int kk=0;kk<2;kk++){
    const float* p = zfin + (size_t)arow*CDE_H + kk*32 + quad*8;
    f16x8 v;
    #pragma unroll
    for(int j=0;j<8;j++) v[j]=(f16)p[j];
    af[kk]=v;
  }
  const f16x8* wp8 = (const f16x8*)Wpf;
  #pragma unroll
  for(int jt=0;jt<4;jt++){
    int n = g*16 + w*4 + jt;
    if(n >= NZ/16) break;
    f32x4 acc={0.f,0.f,0.f,0.f};
    #pragma unroll
    for(int kk=0;kk<2;kk++)
      acc = MFMA(af[kk], wp8[((size_t)n*2+kk)*64+lane], acc);
    int col = n*16+lm;
    float bp = bpred[col];
    #pragma unroll
    for(int r=0;r<4;r++)
      out[(size_t)(m*16+quad*4+r)*NZ + col] = acc[r]+bp;
  }
}

extern "C" void kernel_launch(void* const* d_in, const int* in_sizes, int n_in,
                              void* d_out, int out_size, void* d_ws, size_t ws_size,
                              hipStream_t stream) {
  (void)in_sizes; (void)n_in; (void)out_size; (void)ws_size;
  const float* history = (const float*)d_in[0];
  const float* coeffs  = (const float*)d_in[1];
  const float* times   = (const float*)d_in[2];
  const float* Wih0 = (const float*)d_in[3];
  const float* Whh0 = (const float*)d_in[4];
  const float* bih0 = (const float*)d_in[5];
  const float* bhh0 = (const float*)d_in[6];
  const float* Wih1 = (const float*)d_in[7];
  const float* Whh1 = (const float*)d_in[8];
  const float* bih1 = (const float*)d_in[9];
  const float* bhh1 = (const float*)d_in[10];
  const float* Wmap = (const float*)d_in[11];
  const float* bmap = (const float*)d_in[12];
  const float* gam  = (const float*)d_in[13];
  const float* bet  = (const float*)d_in[14];
  const float* W1   = (const float*)d_in[15];
  const float* b1   = (const float*)d_in[16];
  const float* W2   = (const float*)d_in[17];
  const float* b2   = (const float*)d_in[18];
  const float* Wpred= (const float*)d_in[19];
  const float* bpred= (const float*)d_in[20];
  float* out = (float*)d_out;

  char* ws = (char*)d_ws;
  size_t off=0;
  auto alloc=[&](size_t bytes)->void*{
    void* p = ws+off; off += (bytes+255)&~(size_t)255; return p;
  };
  f16* G      = (f16*)alloc((size_t)SROWS*G4*sizeof(f16));
  f16* seq0   = (f16*)alloc((size_t)SROWS*ENC_H*sizeof(f16));
  f16* fwih0  = (f16*)alloc((size_t)32*3*64*8*sizeof(f16));
  f16* fwhh0  = (f16*)alloc((size_t)32*4*64*8*sizeof(f16));
  f16* fwih1  = (f16*)alloc((size_t)32*4*64*8*sizeof(f16));
  f16* fwhh1  = (f16*)alloc((size_t)32*4*64*8*sizeof(f16));
  f16* fw1    = (f16*)alloc((size_t)8*2*64*8*sizeof(f16));
  f16* fwmap  = (f16*)alloc((size_t)4*4*64*8*sizeof(f16));
  f16* fw2    = (f16*)alloc((size_t)132*4*64*8*sizeof(f16));
  f16* fwpred = (f16*)alloc((size_t)625*2*64*8*sizeof(f16));
  float* z0   = (float*)alloc((size_t)BATCH*CDE_H*sizeof(float));
  float* zfin = (float*)alloc((size_t)BATCH*CDE_H*sizeof(float));

  pack_weights<<<897,256,0,stream>>>(Wih0,Whh0,Wih1,Whh1,W1,Wmap,W2,Wpred,
      fwih0,fwhh0,fwih1,fwhh1,fw1,fwmap,fw2,fwpred);
  gemm_g0<<<SROWS/16,256,0,stream>>>(history,fwih0,bih0,bhh0,G);
  lstm_kernel<<<64,256,0,stream>>>(G,fwhh0,seq0,fwmap,bmap,z0,0);
  gemm_g1<<<SROWS/16,256,0,stream>>>(seq0,fwih1,bih1,bhh1,G);
  lstm_kernel<<<64,256,0,stream>>>(G,fwhh1,nullptr,fwmap,bmap,z0,1);
  cde_kernel<<<64,256,0,stream>>>(z0,coeffs,times,fw1,fw2,b1,b2,gam,bet,zfin);
  gemm_out<<<dim3(64,40),256,0,stream>>>(zfin,fwpred,bpred,out);
}

// Round 2
// 1175.477 us; speedup vs baseline: 1.3863x; 1.3863x over previous
//
#include <hip/hip_runtime.h>
#include <hip/hip_bf16.h>

typedef _Float16 f16;
typedef _Float16 f16x8 __attribute__((ext_vector_type(8)));
typedef _Float16 f16x4 __attribute__((ext_vector_type(4)));
typedef float    f32x4 __attribute__((ext_vector_type(4)));

#define MFMA(a,b,c) __builtin_amdgcn_mfma_f32_16x16x32_f16((a),(b),(c),0,0,0)

#define BATCH 1024
#define T_HIST 50
#define ENC_IN 96
#define ENC_H 128
#define G4 512
#define CDE_H 64
#define NCH 33
#define MLP_H 128
#define NZ 10000
#define NSTEP 16
#define SROWS (BATCH*T_HIST)

__device__ __forceinline__ float sigf(float x){ return 1.f/(1.f+__expf(-x)); }
__device__ __forceinline__ float tanhfast(float x){
  float ax=fabsf(x), e=__expf(-2.f*ax);
  float t=1.f-2.f*e/(1.f+e);
  return x<0.f ? -t : t;
}

// Dormand-Prince tableau (compile-time constants; stage loop is unrolled)
__device__ __constant__ const float RK_A[6][5] = {
  {0.f,0.f,0.f,0.f,0.f},
  {0.2f,0.f,0.f,0.f,0.f},
  {(float)(3.0/40.0),(float)(9.0/40.0),0.f,0.f,0.f},
  {(float)(44.0/45.0),(float)(-56.0/15.0),(float)(32.0/9.0),0.f,0.f},
  {(float)(19372.0/6561.0),(float)(-25360.0/2187.0),(float)(64448.0/6561.0),(float)(-212.0/729.0),0.f},
  {(float)(9017.0/3168.0),(float)(-355.0/33.0),(float)(46732.0/5247.0),(float)(49.0/176.0),(float)(-5103.0/18656.0)}};
__device__ __constant__ const float RK_C[6] = {0.f,0.2f,0.3f,0.8f,(float)(8.0/9.0),1.f};
__device__ __constant__ const float RK_B[6] = {(float)(35.0/384.0),0.f,(float)(500.0/1113.0),(float)(125.0/192.0),(float)(-2187.0/6784.0),(float)(11.0/84.0)};

// ---------------------------------------------------------------------------
// Pack weights (fp32 -> fp16 B-fragment layout [ntile][kk][lane][8])
// ---------------------------------------------------------------------------
__global__ __launch_bounds__(256) void pack_weights(
    const float* __restrict__ wih0, const float* __restrict__ whh0,
    const float* __restrict__ wih1, const float* __restrict__ whh1,
    const float* __restrict__ w1,   const float* __restrict__ wmap,
    const float* __restrict__ w2,   const float* __restrict__ wpred,
    f16* fwih0, f16* fwhh0, f16* fwih1, f16* fwhh1,
    f16* fw1, f16* fwmap, f16* fw2, f16* fwpred)
{
  int bi = blockIdx.x;
  const float* src; f16* dst; int KK, K, n; bool perm=false;
  if      (bi < 32)  { src=wih0;  dst=fwih0;  KK=3; K=96;  n=bi; }
  else if (bi < 64)  { src=whh0;  dst=fwhh0;  KK=4; K=128; n=bi-32; }
  else if (bi < 96)  { src=wih1;  dst=fwih1;  KK=4; K=128; n=bi-64; }
  else if (bi < 128) { src=whh1;  dst=fwhh1;  KK=4; K=128; n=bi-96; }
  else if (bi < 136) { src=w1;    dst=fw1;    KK=2; K=64;  n=bi-128; }
  else if (bi < 140) { src=wmap;  dst=fwmap;  KK=4; K=128; n=bi-136; }
  else if (bi < 272) { src=w2;    dst=fw2;    KK=4; K=128; n=bi-140; perm=true; }
  else               { src=wpred; dst=fwpred; KK=2; K=64;  n=bi-272; }
  int kkI = threadIdx.x>>6, lane = threadIdx.x&63;
  if (kkI >= KK) return;
  int col = n*16 + (lane&15);
  int row = perm ? ((col&63)*NCH + (col>>6)) : col;
  int k0  = kkI*32 + (lane>>4)*8;
  f16* o = dst + (((size_t)n*KK + kkI)*64 + lane)*8;
  const float* s = src + (size_t)row*K + k0;
  #pragma unroll
  for(int j=0;j<8;j++) o[j] = (f16)s[j];
}

// ---------------------------------------------------------------------------
// G0 = history(b-major rows) @ Wih0^T + (bih+bhh), stored t-major [t][b][512] fp16
// ---------------------------------------------------------------------------
__global__ __launch_bounds__(256) void gemm_g0(
    const float* __restrict__ X, const f16* __restrict__ Bf,
    const float* __restrict__ bih, const float* __restrict__ bhh,
    f16* __restrict__ G)
{
  int m = blockIdx.x;
  int w = threadIdx.x>>6, lane = threadIdx.x&63;
  int lm = lane&15, quad = lane>>4;
  int arow = m*16 + lm;
  f16x8 af[3];
  #pragma unroll
  for(int kk=0;kk<3;kk++){
    const float* p = X + (size_t)arow*ENC_IN + kk*32 + quad*8;
    f16x8 v;
    #pragma unroll
    for(int j=0;j<8;j++) v[j] = (f16)p[j];
    af[kk]=v;
  }
  const f16x8* bf8 = (const f16x8*)Bf;
  #pragma unroll
  for(int jt=0;jt<8;jt++){
    int n = w*8 + jt;
    f32x4 acc = {0.f,0.f,0.f,0.f};
    #pragma unroll
    for(int kk=0;kk<3;kk++)
      acc = MFMA(af[kk], bf8[(n*3+kk)*64 + lane], acc);
    int col = n*16 + lm;
    float bias = bih[col] + bhh[col];
    #pragma unroll
    for(int r=0;r<4;r++){
      int srow = m*16 + quad*4 + r;
      int b = srow / T_HIST, t = srow - b*T_HIST;
      G[((size_t)t*BATCH + b)*G4 + col] = (f16)(acc[r] + bias);
    }
  }
}

// G1 = seq0(t-major rows, fp16) @ Wih1^T + (bih+bhh)
__global__ __launch_bounds__(256) void gemm_g1(
    const f16* __restrict__ X, const f16* __restrict__ Bf,
    const float* __restrict__ bih, const float* __restrict__ bhh,
    f16* __restrict__ G)
{
  int m = blockIdx.x;
  int w = threadIdx.x>>6, lane = threadIdx.x&63;
  int lm = lane&15, quad = lane>>4;
  int arow = m*16 + lm;
  f16x8 af[4];
  #pragma unroll
  for(int kk=0;kk<4;kk++)
    af[kk] = *(const f16x8*)(X + (size_t)arow*ENC_H + kk*32 + quad*8);
  const f16x8* bf8 = (const f16x8*)Bf;
  #pragma unroll
  for(int jt=0;jt<8;jt++){
    int n = w*8 + jt;
    f32x4 acc = {0.f,0.f,0.f,0.f};
    #pragma unroll
    for(int kk=0;kk<4;kk++)
      acc = MFMA(af[kk], bf8[(n*4+kk)*64 + lane], acc);
    int col = n*16 + lm;
    float bias = bih[col]+bhh[col];
    #pragma unroll
    for(int r=0;r<4;r++){
      int srow = m*16 + quad*4 + r;
      G[(size_t)srow*G4 + col] = (f16)(acc[r]+bias);
    }
  }
}

// ---------------------------------------------------------------------------
// Persistent LSTM recurrence: 64 blocks x 16 batch rows, 50 steps.
// Gate-input G loaded into regs (overlaps MFMA chain), added in pointwise.
// ---------------------------------------------------------------------------
__global__ __launch_bounds__(256,1) void lstm_kernel(
    const f16* __restrict__ G, const f16* __restrict__ Whhf,
    f16* __restrict__ seqout,
    const f16* __restrict__ Wmapf, const float* __restrict__ bmap,
    float* __restrict__ z0, int layer)
{
  __shared__ __align__(16) f16 hbuf[16][136];
  int w = threadIdx.x>>6, lane = threadIdx.x&63;
  int lm = lane&15, quad = lane>>4;
  int row0 = blockIdx.x*16;

  const f16x8* wf8 = (const f16x8*)Whhf;
  f16x8 Bf[8][4];
  #pragma unroll
  for(int j=0;j<8;j++){
    int n = w + 4*j;
    #pragma unroll
    for(int kk=0;kk<4;kk++)
      Bf[j][kk] = wf8[(n*4+kk)*64 + lane];
  }
  for(int i=threadIdx.x;i<16*136;i+=256) ((f16*)hbuf)[i] = (f16)0.f;
  float cst[2][4];
  #pragma unroll
  for(int mh=0;mh<2;mh++)
    #pragma unroll
    for(int r=0;r<4;r++) cst[mh][r]=0.f;
  __syncthreads();

  for(int t=0;t<T_HIST;t++){
    // issue gate-input loads first (independent of MFMA chain)
    float gin[8][4];
    const f16* Gt = G + ((size_t)t*BATCH + row0)*G4;
    #pragma unroll
    for(int j=0;j<8;j++){
      int col = (w+4*j)*16 + lm;
      #pragma unroll
      for(int r=0;r<4;r++)
        gin[j][r] = (float)Gt[(quad*4+r)*G4 + col];
    }
    f16x8 af[4];
    #pragma unroll
    for(int kk=0;kk<4;kk++)
      af[kk] = *(const f16x8*)&hbuf[lm][kk*32 + quad*8];
    f32x4 acc[8];
    #pragma unroll
    for(int j=0;j<8;j++){ acc[j][0]=0.f;acc[j][1]=0.f;acc[j][2]=0.f;acc[j][3]=0.f; }
    #pragma unroll
    for(int j=0;j<8;j++){
      #pragma unroll
      for(int kk=0;kk<4;kk++)
        acc[j] = MFMA(af[kk], Bf[j][kk], acc[j]);
    }
    __syncthreads();   // all h reads done before rewrite
    #pragma unroll
    for(int mh=0;mh<2;mh++){
      int hcol = (w+4*mh)*16 + lm;
      #pragma unroll
      for(int r=0;r<4;r++){
        float gi = acc[0+mh][r]+gin[0+mh][r], gf = acc[2+mh][r]+gin[2+mh][r];
        float gg = acc[4+mh][r]+gin[4+mh][r], go = acc[6+mh][r]+gin[6+mh][r];
        float c = sigf(gf)*cst[mh][r] + sigf(gi)*tanhfast(gg);
        float h = sigf(go)*tanhfast(c);
        cst[mh][r]=c;
        hbuf[quad*4+r][hcol] = (f16)h;
        if(layer==0)
          seqout[((size_t)t*BATCH + row0 + quad*4 + r)*ENC_H + hcol] = (f16)h;
      }
    }
    __syncthreads();
  }
  if(layer==1){
    f16x8 af[4];
    #pragma unroll
    for(int kk=0;kk<4;kk++)
      af[kk] = *(const f16x8*)&hbuf[lm][kk*32+quad*8];
    const f16x8* mf8 = (const f16x8*)Wmapf;
    float bm = bmap[w*16+lm];
    f32x4 acc = {bm,bm,bm,bm};
    #pragma unroll
    for(int kk=0;kk<4;kk++)
      acc = MFMA(af[kk], mf8[(w*4+kk)*64+lane], acc);
    #pragma unroll
    for(int r=0;r<4;r++)
      z0[(size_t)(row0+quad*4+r)*CDE_H + w*16+lm] = tanhfast(acc[r]);
  }
}

// ---------------------------------------------------------------------------
// Persistent CDE: 64 blocks x 1024 threads (16 waves) x 16 rows.
// Channel loop split over 4 wave-groups (kpart in LDS, reduced inline by the
// next stage's combo). All per-stage global traffic hoisted to init:
// b2 -> LDS, coeffs -> regs, b1 -> reg. 3 barriers/stage.
// ---------------------------------------------------------------------------
__global__ __launch_bounds__(1024,1) void cde_kernel(
    const float* __restrict__ z0, const float* __restrict__ coeffs,
    const float* __restrict__ times,
    const f16* __restrict__ W1f, const f16* __restrict__ W2f,
    const float* __restrict__ b1, const float* __restrict__ b2,
    const float* __restrict__ gamma_, const float* __restrict__ beta_,
    float* __restrict__ zf)
{
  __shared__ __align__(16) float zbuf[16][68];
  __shared__ __align__(16) float kbuf[6][16][68];
  __shared__ __align__(16) float kpart[4][16][68];
  __shared__ __align__(16) f16   znbuf[16][72];
  __shared__ __align__(16) f16   abuf[16][136];
  __shared__ __align__(16) float dxbuf[16][36];
  __shared__ __align__(16) float b2lds[CDE_H*NCH];
  __shared__ __align__(16) f16x8 w1lds[8*2*64];

  int tid = threadIdx.x;
  int w = tid>>6, lane = tid&63, lm = lane&15, quad = lane>>4;
  int row0 = blockIdx.x*16;

  for(int i=tid;i<8*2*64;i+=1024) w1lds[i] = ((const f16x8*)W1f)[i];
  for(int i=tid;i<CDE_H*NCH;i+=1024) b2lds[i] = b2[i];
  { int zr = tid>>6, zc = tid&63;
    zbuf[zr][zc] = z0[(size_t)(row0+zr)*CDE_H + zc]; }

  float t0 = times[0], t1 = times[1];
  float dt = (t1-t0)/(float)NSTEP, seg = (t1-t0)*0.25f;

  // combo/z-update ownership (threads 0..255): row crow, cols ccol..ccol+3
  int crow = (w&3)*4 + quad;
  int ccol = lm*4;
  float gam[4], bet[4];
  if(tid<256){
    #pragma unroll
    for(int j=0;j<4;j++){ gam[j]=gamma_[ccol+j]; bet[j]=beta_[ccol+j]; }
  }
  // dXdt ownership (threads 256..783): one (row,channel) each; all 4 segments in regs
  int ct = tid - 256;
  bool down = (ct>=0 && ct<16*NCH);
  int dr=0, dq=0;
  float c1a[4],c2a[4],c3a[4];
  if(down){
    dr = ct/NCH; dq = ct - dr*NCH;
    #pragma unroll
    for(int i=0;i<4;i++){
      const float* cc = coeffs + (((size_t)(row0+dr)*4 + i)*4)*NCH + dq;
      c1a[i]=cc[NCH]; c2a[i]=cc[2*NCH]; c3a[i]=cc[3*NCH];
    }
  }
  // gemm1 bias (waves 0..7)
  float b1r = b1[(w&7)*16 + lm];
  // gemm2 wave-group assignment
  int g = w>>2, wsub = w&3;
  int h2 = wsub*16 + lm;
  const f16x8* w2f8 = (const f16x8*)W2f;
  __syncthreads();

  for(int istep=0;istep<NSTEP;istep++){
    #pragma unroll
    for(int s=0;s<6;s++){
      float ts = t0 + ((float)istep + RK_C[s])*dt;
      // ---- phase A: combo+LN (threads<256) and dXdt (threads 256..783)
      if(tid<256){
        f32x4 v = *(const f32x4*)&zbuf[crow][ccol];
        if(s>0){
          // reduce previous stage's partials inline, store for later stages
          f32x4 kv = *(const f32x4*)&kpart[0][crow][ccol];
          #pragma unroll
          for(int gg2=1;gg2<4;gg2++){
            f32x4 kp = *(const f32x4*)&kpart[gg2][crow][ccol];
            kv[0]+=kp[0]; kv[1]+=kp[1]; kv[2]+=kp[2]; kv[3]+=kp[3];
          }
          *(f32x4*)&kbuf[s-1][crow][ccol] = kv;
          float aj = dt*RK_A[s][s-1];
          v[0]+=aj*kv[0]; v[1]+=aj*kv[1]; v[2]+=aj*kv[2]; v[3]+=aj*kv[3];
          #pragma unroll
          for(int j=0;j<5;j++){
            if(j < s-1){
              float a2 = dt*RK_A[s][j];
              f32x4 k2 = *(const f32x4*)&kbuf[j][crow][ccol];
              v[0]+=a2*k2[0]; v[1]+=a2*k2[1]; v[2]+=a2*k2[2]; v[3]+=a2*k2[3];
            }
          }
        }
        float sum = v[0]+v[1]+v[2]+v[3];
        float ssq = v[0]*v[0]+v[1]*v[1]+v[2]*v[2]+v[3]*v[3];
        #pragma unroll
        for(int m=1;m<16;m<<=1){
          sum += __shfl_xor(sum, m);
          ssq += __shfl_xor(ssq, m);
        }
        float mu   = sum*(1.f/CDE_H);
        float var  = ssq*(1.f/CDE_H) - mu*mu;
        float rstd = rsqrtf(var + 1e-5f);
        f16x4 zn;
        #pragma unroll
        for(int j=0;j<4;j++)
          zn[j] = (f16)(((v[j]-mu)*rstd)*gam[j] + bet[j]);
        *(f16x4*)&znbuf[crow][ccol] = zn;
      } else if(down){
        int idxt = (int)floorf((ts-t0)/seg);
        idxt = min(3, max(0, idxt));
        float u = ts - (t0 + (float)idxt*seg);
        float C1 = idxt==0?c1a[0]:idxt==1?c1a[1]:idxt==2?c1a[2]:c1a[3];
        float C2 = idxt==0?c2a[0]:idxt==1?c2a[1]:idxt==2?c2a[2]:c2a[3];
        float C3 = idxt==0?c3a[0]:idxt==1?c3a[1]:idxt==2?c3a[2]:c3a[3];
        dxbuf[dr][dq] = C1 + 2.f*C2*u + 3.f*C3*u*u;
      }
      __syncthreads();
      // ---- phase B: GEMM1 relu(zn @ W1^T + b1) on waves 0..7
      if(w<8){
        f16x8 af1[2];
        #pragma unroll
        for(int kk=0;kk<2;kk++)
          af1[kk] = *(const f16x8*)&znbuf[lm][kk*32+quad*8];
        f32x4 acc={0.f,0.f,0.f,0.f};
        #pragma unroll
        for(int kk=0;kk<2;kk++)
          acc = MFMA(af1[kk], w1lds[(w*2+kk)*64+lane], acc);
        int col = w*16+lm;
        #pragma unroll
        for(int r=0;r<4;r++){
          float a = acc[r]+b1r;
          abuf[quad*4+r][col] = (f16)(a>0.f? a:0.f);
        }
      }
      __syncthreads();
      // ---- phase C: GEMM2 + tanh + einsum, channels split over 4 wave-groups
      {
        f16x8 af2[4];
        #pragma unroll
        for(int kk=0;kk<4;kk++)
          af2[kk] = *(const f16x8*)&abuf[lm][kk*32+quad*8];
        f32x4 kacc = {0.f,0.f,0.f,0.f};
        int n0 = g*4 + wsub;
        f16x8 bc[4];
        #pragma unroll
        for(int kk=0;kk<4;kk++) bc[kk] = w2f8[((size_t)n0*4+kk)*64+lane];
        for(int j=g; j<NCH; j+=4){
          int jn = j+4;
          f16x8 bn[4];
          if(jn<NCH){
            int n2 = jn*4+wsub;
            #pragma unroll
            for(int kk=0;kk<4;kk++) bn[kk] = w2f8[((size_t)n2*4+kk)*64+lane];
          }
          float dxr[4];
          #pragma unroll
          for(int r=0;r<4;r++) dxr[r] = dxbuf[quad*4+r][j];
          float b2v = b2lds[h2*NCH+j];
          f32x4 aA={0.f,0.f,0.f,0.f}, aB={b2v,b2v,b2v,b2v};
          aA = MFMA(af2[0],bc[0],aA); aA = MFMA(af2[1],bc[1],aA);
          aB = MFMA(af2[2],bc[2],aB); aB = MFMA(af2[3],bc[3],aB);
          #pragma unroll
          for(int r=0;r<4;r++){
            float f = tanhfast(aA[r]+aB[r]);
            kacc[r] += f*dxr[r];
          }
          #pragma unroll
          for(int kk=0;kk<4;kk++) bc[kk]=bn[kk];
        }
        #pragma unroll
        for(int r=0;r<4;r++)
          kpart[g][quad*4+r][h2] = kacc[r];
      }
      __syncthreads();
    }
    // ---- z update (threads<256), stage-5 partials reduced inline
    if(tid<256){
      f32x4 v = *(const f32x4*)&zbuf[crow][ccol];
      f32x4 k5 = *(const f32x4*)&kpart[0][crow][ccol];
      #pragma unroll
      for(int gg2=1;gg2<4;gg2++){
        f32x4 kp = *(const f32x4*)&kpart[gg2][crow][ccol];
        k5[0]+=kp[0]; k5[1]+=kp[1]; k5[2]+=kp[2]; k5[3]+=kp[3];
      }
      float b5 = dt*RK_B[5];
      v[0]+=b5*k5[0]; v[1]+=b5*k5[1]; v[2]+=b5*k5[2]; v[3]+=b5*k5[3];
      #pragma unroll
      for(int j=0;j<5;j++){
        if(j==1) continue;
        float bj = dt*RK_B[j];
        f32x4 kv = *(const f32x4*)&kbuf[j][crow][ccol];
        v[0]+=bj*kv[0]; v[1]+=bj*kv[1]; v[2]+=bj*kv[2]; v[3]+=bj*kv[3];
      }
      *(f32x4*)&zbuf[crow][ccol] = v;
      if(istep==NSTEP-1)
        *(f32x4*)(zf + (size_t)(row0+crow)*CDE_H + ccol) = v;
    }
    __syncthreads();
  }
}

// ---------------------------------------------------------------------------
// out = zf @ Wpred^T + bpred   (1024 x 10000, fp32 out)
// ---------------------------------------------------------------------------
__global__ __launch_bounds__(256) void gemm_out(
    const float* __restrict__ zfin, const f16* __restrict__ Wpf,
    const float* __restrict__ bpred, float* __restrict__ out)
{
  int m = blockIdx.x, g = blockIdx.y;
  int w = threadIdx.x>>6, lane = threadIdx.x&63, lm=lane&15, quad=lane>>4;
  int arow = m*16+lm;
  f16x8 af[2];
  #pragma unroll
  for(int kk=0;kk<2;kk++){
    const float* p = zfin + (size_t)arow*CDE_H + kk*32 + quad*8;
    f16x8 v;
    #pragma unroll
    for(int j=0;j<8;j++) v[j]=(f16)p[j];
    af[kk]=v;
  }
  const f16x8* wp8 = (const f16x8*)Wpf;
  #pragma unroll
  for(int jt=0;jt<4;jt++){
    int n = g*16 + w*4 + jt;
    if(n >= NZ/16) break;
    f32x4 acc={0.f,0.f,0.f,0.f};
    #pragma unroll
    for(int kk=0;kk<2;kk++)
      acc = MFMA(af[kk], wp8[((size_t)n*2+kk)*64+lane], acc);
    int col = n*16+lm;
    float bp = bpred[col];
    #pragma unroll
    for(int r=0;r<4;r++)
      out[(size_t)(m*16+quad*4+r)*NZ + col] = acc[r]+bp;
  }
}

extern "C" void kernel_launch(void* const* d_in, const int* in_sizes, int n_in,
                              void* d_out, int out_size, void* d_ws, size_t ws_size,
                              hipStream_t stream) {
  (void)in_sizes; (void)n_in; (void)out_size; (void)ws_size;
  const float* history = (const float*)d_in[0];
  const float* coeffs  = (const float*)d_in[1];
  const float* times   = (const float*)d_in[2];
  const float* Wih0 = (const float*)d_in[3];
  const float* Whh0 = (const float*)d_in[4];
  const float* bih0 = (const float*)d_in[5];
  const float* bhh0 = (const float*)d_in[6];
  const float* Wih1 = (const float*)d_in[7];
  const float* Whh1 = (const float*)d_in[8];
  const float* bih1 = (const float*)d_in[9];
  const float* bhh1 = (const float*)d_in[10];
  const float* Wmap = (const float*)d_in[11];
  const float* bmap = (const float*)d_in[12];
  const float* gam  = (const float*)d_in[13];
  const float* bet  = (const float*)d_in[14];
  const float* W1   = (const float*)d_in[15];
  const float* b1   = (const float*)d_in[16];
  const float* W2   = (const float*)d_in[17];
  const float* b2   = (const float*)d_in[18];
  const float* Wpred= (const float*)d_in[19];
  const float* bpred= (const float*)d_in[20];
  float* out = (float*)d_out;

  char* ws = (char*)d_ws;
  size_t off=0;
  auto alloc=[&](size_t bytes)->void*{
    void* p = ws+off; off += (bytes+255)&~(size_t)255; return p;
  };
  f16* G      = (f16*)alloc((size_t)SROWS*G4*sizeof(f16));
  f16* seq0   = (f16*)alloc((size_t)SROWS*ENC_H*sizeof(f16));
  f16* fwih0  = (f16*)alloc((size_t)32*3*64*8*sizeof(f16));
  f16* fwhh0  = (f16*)alloc((size_t)32*4*64*8*sizeof(f16));
  f16* fwih1  = (f16*)alloc((size_t)32*4*64*8*sizeof(f16));
  f16* fwhh1  = (f16*)alloc((size_t)32*4*64*8*sizeof(f16));
  f16* fw1    = (f16*)alloc((size_t)8*2*64*8*sizeof(f16));
  f16* fwmap  = (f16*)alloc((size_t)4*4*64*8*sizeof(f16));
  f16* fw2    = (f16*)alloc((size_t)132*4*64*8*sizeof(f16));
  f16* fwpred = (f16*)alloc((size_t)625*2*64*8*sizeof(f16));
  float* z0   = (float*)alloc((size_t)BATCH*CDE_H*sizeof(float));
  float* zfin = (float*)alloc((size_t)BATCH*CDE_H*sizeof(float));

  pack_weights<<<897,256,0,stream>>>(Wih0,Whh0,Wih1,Whh1,W1,Wmap,W2,Wpred,
      fwih0,fwhh0,fwih1,fwhh1,fw1,fwmap,fw2,fwpred);
  gemm_g0<<<SROWS/16,256,0,stream>>>(history,fwih0,bih0,bhh0,G);
  lstm_kernel<<<64,256,0,stream>>>(G,fwhh0,seq0,fwmap,bmap,z0,0);
  gemm_g1<<<SROWS/16,256,0,stream>>>(seq0,fwih1,bih1,bhh1,G);
  lstm_kernel<<<64,256,0,stream>>>(G,fwhh1,nullptr,fwmap,bmap,z0,1);
  cde_kernel<<<64,1024,0,stream>>>(z0,coeffs,times,fw1,fw2,b1,b2,gam,bet,zfin);
  gemm_out<<<dim3(64,40),256,0,stream>>>(zfin,fwpred,bpred,out);
}